// Round 7
// baseline (942.408 us; speedup 1.0000x reference)
//
#include <hip/hip_runtime.h>

typedef __attribute__((ext_vector_type(4))) float f4;
typedef __attribute__((ext_vector_type(2))) float f2;

#define NP 128      // nodes per graph
#define NE 2048     // edges per graph
#define NFEAT 128
#define LW 33       // row stride (words) for activation buffers
#define NT 1024     // octet per node: node = t>>3, lane owns 4 cols

// ---- in-place aggregation: zo[c] <- dis[c]*(zs[c] + sum_in zs[src]) + bias.
// 8 lanes/node, 4-col slice each, f2 reads (same pattern as the 117us R1 kernel,
// halved per-lane). Padded-4 CSR, pad id 128 -> zero row.
__device__ __forceinline__ void aggregate(float* zo, const float* __restrict__ bias,
    const unsigned char* inlist, const int* offs, const int* indeg,
    const float* diss, int t)
{
  const int c = t >> 3;
  const int j0 = (t & 7) * 4;
  float s[4];
  {
    f2 v0 = *(const f2*)&zo[c*LW + j0];
    f2 v1 = *(const f2*)&zo[c*LW + j0 + 2];
    s[0] = v0[0]; s[1] = v0[1]; s[2] = v1[0]; s[3] = v1[1];
  }
  const int ps = offs[c];
  const int pe = ps + ((indeg[c] + 3) & ~3);
  for (int p = ps; p < pe; p += 4) {
    const unsigned w = *(const unsigned*)(inlist + p);   // 4 neighbor ids
#pragma unroll
    for (int b = 0; b < 4; ++b) {
      const int rr = (w >> (8*b)) & 255;
      f2 v0 = *(const f2*)&zo[rr*LW + j0];
      f2 v1 = *(const f2*)&zo[rr*LW + j0 + 2];
      s[0] += v0[0]; s[1] += v0[1]; s[2] += v1[0]; s[3] += v1[1];
    }
  }
  __syncthreads();
  const float d = diss[c];
#pragma unroll
  for (int u = 0; u < 4; ++u)
    zo[c*LW + j0 + u] = d * s[u] + bias[j0 + u];
  __syncthreads();
}

// ---- 32x32 matmul: dst[n][j] = (sum_k src[n][k]*W[k][j]) * dis[n]
// one row per octet, 4 cols/lane; src b32 octet-broadcast, W f4 from Wl.
__device__ __forceinline__ void mm32(const float* src, float* dst,
    const float* __restrict__ Wg, float* Wl, const float* diss, int t)
{
  if (t < 256) {
    const int k = t >> 3, jq = t & 7;
    *(f4*)&Wl[k*36 + jq*4] = *(const f4*)(Wg + (size_t)k*32 + jq*4);
  }
  __syncthreads();
  const int n = t >> 3, j0 = (t & 7) * 4;
  f4 acc = {0.f, 0.f, 0.f, 0.f};
#pragma unroll
  for (int k = 0; k < 32; ++k) {
    const float a = src[n*LW + k];
    const f4 w = *(const f4*)&Wl[k*36 + j0];
    acc += a * w;
  }
  const float d = diss[n];
#pragma unroll
  for (int u = 0; u < 4; ++u) dst[n*LW + j0 + u] = acc[u] * d;
}

__global__ __launch_bounds__(NT, 8) void k1_gcn(
    const float* __restrict__ x, const float* __restrict__ eattr,
    const int* __restrict__ eidx,
    const float* __restrict__ W1, const float* __restrict__ b1,
    const float* __restrict__ W2, const float* __restrict__ b2,
    const float* __restrict__ W3, const float* __restrict__ b3,
    const float* __restrict__ W4, const float* __restrict__ b4,
    const float* __restrict__ c1w, const float* __restrict__ c1b,
    const float* __restrict__ c2w, const float* __restrict__ c2b,
    float* __restrict__ dense_out, int E_total)
{
  __shared__ float o1[129*LW];
  __shared__ float o2[129*LW];   // also x-stage during layer 1
  __shared__ float o3[129*LW];
  __shared__ float Wl[32*36];
  __shared__ float o4s[129];
  __shared__ float xedge[NP];
  __shared__ float diss[NP];
  __shared__ int indeg[NP];
  __shared__ int offs[NP];
  __shared__ int curp[NP];
  __shared__ unsigned char inlist[2432];  // sum ceil4(deg) <= 2048+3*128
  __shared__ int selidx[20];
  __shared__ float c1buf[16 * 20];
  __shared__ float mpbuf[16 * 10];

  const int t = threadIdx.x;
  const int g = blockIdx.x;
  const int ebase = g * NE;
  const int nbase = g * NP;
  const int oc = t >> 3, l = t & 7;   // octet-per-node mapping

  if (t < NP) { xedge[t] = 0.f; indeg[t] = 0; curp[t] = 0; }
  if (t < LW) { o1[128*LW + t] = 0.f; o2[128*LW + t] = 0.f; o3[128*LW + t] = 0.f; }
  if (t == 0) o4s[128] = 0.f;
  if (t < 608) ((int*)inlist)[t] = (int)0x80808080u;   // pad id 128
  __syncthreads();

  // ---- edge pass 1: x_edge (over src), in-degree (over dst)
  int er[2], ec[2];
#pragma unroll
  for (int i = 0; i < 2; ++i) {
    const int e = t + i * NT;
    er[i] = eidx[ebase + e] - nbase;
    ec[i] = eidx[E_total + ebase + e] - nbase;
    atomicAdd(&xedge[er[i]], eattr[ebase + e]);
    atomicAdd(&indeg[ec[i]], 1);
  }
  __syncthreads();

  // ---- padded-4 CSR offsets; dis = rsqrt(1+deg)
  if (t < NP) {
    int s = 0;
    for (int m = 0; m < NP; ++m) s += (m < t) ? ((indeg[m] + 3) & ~3) : 0;
    offs[t] = s;
    diss[t] = rsqrtf(1.0f + (float)indeg[t]);
  }
  __syncthreads();

  // ---- edge pass 2: fill dst-CSR src list (pad slots stay 128)
#pragma unroll
  for (int i = 0; i < 2; ++i) {
    const int p = atomicAdd(&curp[ec[i]], 1);
    inlist[offs[ec[i]] + p] = (unsigned char)er[i];
  }

  // ---- layer 1: zs1 = ([x | x_edge] @ W1) * dis -> o1 ; x staged in o2 region
  {
    float* xs = o2;
    const float* xrow = x + (size_t)(nbase + oc) * NFEAT;
    f4 pv = *(const f4*)(xrow + l * 4);        // chunk 0, cols 4l..4l+3
    f4 acc = {0.f, 0.f, 0.f, 0.f};

    for (int fc = 0; fc < NFEAT; fc += 32) {
      __syncthreads();
      { // write prefetched slice (scalar stores, rotating banks)
        float* xd = xs + oc * LW + l * 4;
#pragma unroll
        for (int j = 0; j < 4; ++j) xd[j] = pv[j];
      }
      if (t < 256) {  // stage W1 chunk
        const int k = t >> 3, jq = t & 7;
        *(f4*)&Wl[k*36 + jq*4] = *(const f4*)(W1 + (size_t)(fc + k) * 32 + jq * 4);
      }
      if (fc < 96) {  // prefetch next chunk slice
        pv = *(const f4*)(xrow + fc + 32 + l * 4);
      }
      __syncthreads();
#pragma unroll
      for (int k = 0; k < 32; ++k) {
        const float a = xs[oc*LW + k];          // octet-broadcast
        const f4 w = *(const f4*)&Wl[k*36 + l*4];
        acc += a * w;
      }
    }
    const f4 wlast = *(const f4*)(W1 + 128*32 + l*4);
    const float xe = xedge[oc], dd = diss[oc];
#pragma unroll
    for (int u = 0; u < 4; ++u)
      o1[oc*LW + l*4 + u] = (acc[u] + xe * wlast[u]) * dd;
  }
  __syncthreads();

  aggregate(o1, b1, inlist, offs, indeg, diss, t);   // o1 = layer-1 out
  mm32(o1, o2, W2, Wl, diss, t);
  __syncthreads();
  aggregate(o2, b2, inlist, offs, indeg, diss, t);   // o2 = layer-2 out
  mm32(o2, o3, W3, Wl, diss, t);
  __syncthreads();
  aggregate(o3, b3, inlist, offs, indeg, diss, t);   // o3 = layer-3 out

  // ---- layer 4 (width 1): octet partial dot + shfl reduce
  {
    const f4 v = { o3[oc*LW + l*4], o3[oc*LW + l*4 + 1],
                   o3[oc*LW + l*4 + 2], o3[oc*LW + l*4 + 3] };
    const f4 w = *(const f4*)(W4 + l*4);
    float s = v[0]*w[0] + v[1]*w[1] + v[2]*w[2] + v[3]*w[3];
    s += __shfl_xor(s, 1);
    s += __shfl_xor(s, 2);
    s += __shfl_xor(s, 4);
    if (l == 0) o4s[oc] = s * diss[oc];
  }
  __syncthreads();
  float s4 = 0.f;
  if (t < NP) {
    s4 = o4s[t];
    const int ps = offs[t], pe = ps + ((indeg[t] + 3) & ~3);
    for (int p = ps; p < pe; p += 4) {
      const unsigned w = *(const unsigned*)(inlist + p);
#pragma unroll
      for (int b = 0; b < 4; ++b) s4 += o4s[(w >> (8*b)) & 255];
    }
  }
  __syncthreads();
  if (t < NP) o4s[t] = diss[t] * s4 + b4[0];
  __syncthreads();

  // ---- top-k (k=20) rank counting: matches lax.top_k (desc, stable ties)
  if (t < NP) {
    const float sn_ = o4s[t];
    int cnt = 0;
    for (int m = 0; m < NP; ++m) {
      const float sm = o4s[m];
      cnt += (sm > sn_ || (sm == sn_ && m < t)) ? 1 : 0;
    }
    if (cnt < 20) selidx[cnt] = t;
  }
  __syncthreads();

  // ---- c1: [16 ch][20 k], relu
  if (t < 320) {
    const int k = t % 20, ch = t / 20;
    const int nd = selidx[k];
    const float* wr = c1w + ch * 97;
    float s = c1b[ch];
#pragma unroll 8
    for (int d = 0; d < 32; ++d) s += o1[nd*LW + d] * wr[d];
#pragma unroll 8
    for (int d = 0; d < 32; ++d) s += o2[nd*LW + d] * wr[32 + d];
#pragma unroll 8
    for (int d = 0; d < 32; ++d) s += o3[nd*LW + d] * wr[64 + d];
    s += o4s[nd] * wr[96];
    c1buf[ch * 20 + k] = fmaxf(s, 0.f);
  }
  __syncthreads();
  if (t < 160) {  // maxpool(2,2) -> [16][10]
    const int ch = t / 10, p = t % 10;
    mpbuf[ch * 10 + p] = fmaxf(c1buf[ch * 20 + 2*p], c1buf[ch * 20 + 2*p + 1]);
  }
  __syncthreads();
  if (t < 192) {  // conv1d 16->32, k=5 -> [32][6], relu
    const int oc2 = t / 6, tt = t % 6;
    float s = c2b[oc2];
#pragma unroll
    for (int ic = 0; ic < 16; ++ic) {
      const float* wr = c2w + (oc2 * 16 + ic) * 5;
#pragma unroll
      for (int u = 0; u < 5; ++u) s += mpbuf[ic * 10 + tt + u] * wr[u];
    }
    dense_out[(size_t)g * 192 + t] = fmaxf(s, 0.f);
  }
}

// ---- K2: d1 = relu(dense[1024,192] @ out_w[192,1024] + out_b), 64x64 tiles
__global__ __launch_bounds__(256) void k2_d1(const float* __restrict__ dense,
    const float* __restrict__ out_w, const float* __restrict__ out_b,
    float* __restrict__ d1)
{
  __shared__ float As[32 * 68];  // [k][m] transposed
  __shared__ float Bs[32 * 68];  // [k][n]
  const int t = threadIdx.x;
  const int n0 = blockIdx.x * 64, m0 = blockIdx.y * 64;
  const int r = t & 15, c = t >> 4;
  float acc[4][4];
#pragma unroll
  for (int i = 0; i < 4; ++i)
#pragma unroll
    for (int u = 0; u < 4; ++u) acc[i][u] = 0.f;

  for (int kk = 0; kk < 192; kk += 32) {
    __syncthreads();
    {
      const int m = t >> 2;
      const int kq = (t & 3) * 2;
#pragma unroll
      for (int qq = 0; qq < 2; ++qq) {
        f4 v = *(const f4*)(dense + (size_t)(m0 + m) * 192 + kk + (kq + qq) * 4);
        const int k0 = (kq + qq) * 4;
        As[(k0+0)*68 + m] = v[0]; As[(k0+1)*68 + m] = v[1];
        As[(k0+2)*68 + m] = v[2]; As[(k0+3)*68 + m] = v[3];
      }
    }
    {
      const int k = t >> 3;
      const int nq = (t & 7) * 2;
#pragma unroll
      for (int qq = 0; qq < 2; ++qq) {
        f4 v = *(const f4*)(out_w + (size_t)(kk + k) * 1024 + n0 + (nq + qq) * 4);
        *(f4*)&Bs[k*68 + (nq + qq) * 4] = v;
      }
    }
    __syncthreads();
#pragma unroll
    for (int k = 0; k < 32; ++k) {
      f4 a = *(const f4*)&As[k*68 + r*4];
      f4 b = *(const f4*)&Bs[k*68 + c*4];
#pragma unroll
      for (int i = 0; i < 4; ++i)
#pragma unroll
        for (int u = 0; u < 4; ++u) acc[i][u] += a[i] * b[u];
    }
  }
  f4 bb = *(const f4*)(out_b + n0 + c*4);
#pragma unroll
  for (int i = 0; i < 4; ++i) {
    f4 o;
#pragma unroll
    for (int u = 0; u < 4; ++u) o[u] = fmaxf(acc[i][u] + bb[u], 0.f);
    *(f4*)(d1 + (size_t)(m0 + r*4 + i) * 1024 + n0 + c*4) = o;
  }
}

// ---- K3: d2 = d1[1024,1024] @ h1_w[1024,128] + h1_b, split-K with atomics
__global__ __launch_bounds__(256) void k3_init(const float* __restrict__ h1_b,
    float* __restrict__ d2)
{
  const int i = blockIdx.x * 256 + threadIdx.x;
  d2[i] = h1_b[i & 127];
}

__global__ __launch_bounds__(256) void k3_d2(const float* __restrict__ d1,
    const float* __restrict__ h1_w, float* __restrict__ d2)
{
  __shared__ float As[32 * 36];
  __shared__ float Bs[32 * 36];
  const int t = threadIdx.x;
  const int m0 = blockIdx.x * 32, n0 = blockIdx.y * 32, ks = blockIdx.z * 128;
  const int r = t & 15, c = t >> 4;
  float a00 = 0.f, a01 = 0.f, a10 = 0.f, a11 = 0.f;

  for (int kk = ks; kk < ks + 128; kk += 32) {
    __syncthreads();
    {
      const int m = t >> 3, kq = t & 7;
      f4 v = *(const f4*)(d1 + (size_t)(m0 + m) * 1024 + kk + kq * 4);
      const int k0 = kq * 4;
      As[(k0+0)*36 + m] = v[0]; As[(k0+1)*36 + m] = v[1];
      As[(k0+2)*36 + m] = v[2]; As[(k0+3)*36 + m] = v[3];
    }
    {
      const int k = t >> 3, nq = t & 7;
      f4 v = *(const f4*)(h1_w + (size_t)(kk + k) * 128 + n0 + nq * 4);
      *(f4*)&Bs[k*36 + nq*4] = v;
    }
    __syncthreads();
#pragma unroll
    for (int k = 0; k < 32; ++k) {
      const float a0 = As[k*36 + r*2], a1 = As[k*36 + r*2 + 1];
      const float b0 = Bs[k*36 + c*2], b1 = Bs[k*36 + c*2 + 1];
      a00 += a0*b0; a01 += a0*b1;
      a10 += a1*b0; a11 += a1*b1;
    }
  }
  atomicAdd(d2 + (size_t)(m0 + r*2 + 0) * 128 + n0 + c*2 + 0, a00);
  atomicAdd(d2 + (size_t)(m0 + r*2 + 0) * 128 + n0 + c*2 + 1, a01);
  atomicAdd(d2 + (size_t)(m0 + r*2 + 1) * 128 + n0 + c*2 + 0, a10);
  atomicAdd(d2 + (size_t)(m0 + r*2 + 1) * 128 + n0 + c*2 + 1, a11);
}

// ---- K4: logits = relu(d2) @ h2_w + h2_b, then log_softmax
__global__ __launch_bounds__(256) void k4_out(const float* __restrict__ d2,
    const float* __restrict__ h2_w, const float* __restrict__ h2_b,
    float* __restrict__ outp)
{
  __shared__ float lbuf[16][17];
  const int t = threadIdx.x;
  const int gl = t >> 4, cc = t & 15;
  const int g = blockIdx.x * 16 + gl;
  float s = h2_b[cc];
  for (int k4 = 0; k4 < 32; ++k4) {
    f4 v = *(const f4*)(d2 + (size_t)g * 128 + k4 * 4);
#pragma unroll
    for (int i = 0; i < 4; ++i) {
      const float rv = fmaxf(v[i], 0.f);
      s += rv * h2_w[(k4*4 + i) * 16 + cc];
    }
  }
  lbuf[gl][cc] = s;
  __syncthreads();
  float mx = -1e30f;
#pragma unroll
  for (int j = 0; j < 16; ++j) mx = fmaxf(mx, lbuf[gl][j]);
  float se = 0.f;
#pragma unroll
  for (int j = 0; j < 16; ++j) se += expf(lbuf[gl][j] - mx);
  outp[(size_t)g * 16 + cc] = s - mx - logf(se);
}

extern "C" void kernel_launch(void* const* d_in, const int* in_sizes, int n_in,
                              void* d_out, int out_size, void* d_ws, size_t ws_size,
                              hipStream_t stream) {
  const float* x     = (const float*)d_in[0];
  const float* eattr = (const float*)d_in[1];
  const int*   eidx  = (const int*)d_in[2];
  const float* W1 = (const float*)d_in[3];  const float* b1 = (const float*)d_in[4];
  const float* W2 = (const float*)d_in[5];  const float* b2 = (const float*)d_in[6];
  const float* W3 = (const float*)d_in[7];  const float* b3 = (const float*)d_in[8];
  const float* W4 = (const float*)d_in[9];  const float* b4 = (const float*)d_in[10];
  const float* c1w = (const float*)d_in[11]; const float* c1b = (const float*)d_in[12];
  const float* c2w = (const float*)d_in[13]; const float* c2b = (const float*)d_in[14];
  const float* out_w = (const float*)d_in[15]; const float* out_b = (const float*)d_in[16];
  const float* h1_w  = (const float*)d_in[17]; const float* h1_b  = (const float*)d_in[18];
  const float* h2_w  = (const float*)d_in[19]; const float* h2_b  = (const float*)d_in[20];

  const int E_total = in_sizes[1];            // 2,097,152 edges
  const int N_nodes = in_sizes[0] / NFEAT;    // 131,072
  const int G = N_nodes / NP;                 // 1024 graphs

  float* ws    = (float*)d_ws;
  float* dense = ws;                          // [G,192]
  float* d1    = ws + (size_t)G * 192;        // [G,1024]
  float* d2    = d1 + (size_t)G * 1024;       // [G,128]

  k1_gcn<<<G, NT, 0, stream>>>(x, eattr, eidx, W1, b1, W2, b2, W3, b3, W4, b4,
                               c1w, c1b, c2w, c2b, dense, E_total);
  k2_d1<<<dim3(16, G / 64), 256, 0, stream>>>(dense, out_w, out_b, d1);
  k3_init<<<(G * 128) / 256, 256, 0, stream>>>(h1_b, d2);
  k3_d2<<<dim3(G / 32, 4, 8), 256, 0, stream>>>(d1, h1_w, d2);
  k4_out<<<G / 16, 256, 0, stream>>>(d2, h2_w, h2_b, (float*)d_out);
}

// Round 8
// 137.735 us; speedup vs baseline: 6.8422x; 6.8422x over previous
//
#include <hip/hip_runtime.h>

typedef __attribute__((ext_vector_type(4))) float f4;
typedef __attribute__((ext_vector_type(2))) float f2;

#define NP 128      // nodes per graph
#define NE 2048     // edges per graph
#define NFEAT 128
#define LW 33       // row stride (words) for activation buffers
#define NT 512

// ---- in-place aggregation (VERBATIM from the 117us R1 kernel):
// zo[c][j] <- dis[c]*(zs[c][j] + sum_in zs[r][j]) + bias[j]
// 4 lanes/node, 8-col slice, f2 reads, padded-4 CSR (pad id 128 -> zero row).
__device__ __forceinline__ void aggregate(float* zo, const float* __restrict__ bias,
    const unsigned char* inlist, const int* offs4, const int* indeg,
    const float* diss, int t)
{
  const int c = t >> 2;
  const int j0 = (t & 3) * 8;
  float s[8];
#pragma unroll
  for (int u = 0; u < 8; ++u) s[u] = zo[c*LW + j0 + u];
  const int ps = offs4[c];
  const int pe = ps + ((indeg[c] + 3) & ~3);
  for (int p = ps; p < pe; p += 4) {
    const unsigned w = *(const unsigned*)(inlist + p);   // 4 neighbor ids at once
#pragma unroll
    for (int b = 0; b < 4; ++b) {
      const int rr = (w >> (8*b)) & 255;
#pragma unroll
      for (int u = 0; u < 8; ++u) s[u] += zo[rr*LW + j0 + u];
    }
  }
  __syncthreads();
  const float d = diss[c];
#pragma unroll
  for (int u = 0; u < 8; ++u) zo[c*LW + j0 + u] = d * s[u] + bias[j0 + u];
  __syncthreads();
}

// ---- 32x32 matmul (VERBATIM R1): dst[n][j] = (sum_f src[n][f]*W[f][j]) * dis[n]
__device__ __forceinline__ void mm32(const float* src, float* dst,
    const float* __restrict__ Wg, float* Wl, const float* diss, int t)
{
  if (t < 256) {                       // stage W [32][32] -> Wl stride 36
    const int k = t >> 3, jq = t & 7;
    *(f4*)&Wl[k*36 + jq*4] = *(const f4*)(Wg + (size_t)k*32 + jq*4);
  }
  __syncthreads();
  const int n2 = t & 63, c4 = t >> 6;
  float acc[2][4];
#pragma unroll
  for (int i = 0; i < 2; ++i)
#pragma unroll
    for (int u = 0; u < 4; ++u) acc[i][u] = 0.f;
#pragma unroll
  for (int k = 0; k < 32; ++k) {
    f4 w = *(const f4*)&Wl[k*36 + c4*4];
    const float a0 = src[n2*LW + k];
    const float a1 = src[(n2+64)*LW + k];
#pragma unroll
    for (int u = 0; u < 4; ++u) { acc[0][u] += a0 * w[u]; acc[1][u] += a1 * w[u]; }
  }
#pragma unroll
  for (int i = 0; i < 2; ++i) {
    const int n = n2 + 64*i;
    const float dd = diss[n];
#pragma unroll
    for (int u = 0; u < 4; ++u) dst[n*LW + c4*4 + u] = acc[i][u] * dd;
  }
}

__global__ __launch_bounds__(NT, 4) void k1_gcn(
    const float* __restrict__ x, const float* __restrict__ eattr,
    const int* __restrict__ eidx,
    const float* __restrict__ W1, const float* __restrict__ b1,
    const float* __restrict__ W2, const float* __restrict__ b2,
    const float* __restrict__ W3, const float* __restrict__ b3,
    const float* __restrict__ W4, const float* __restrict__ b4,
    const float* __restrict__ c1w, const float* __restrict__ c1b,
    const float* __restrict__ c2w, const float* __restrict__ c2b,
    float* __restrict__ dense_out, int E_total)
{
  __shared__ float o1[129*LW];
  __shared__ float o2[129*LW];   // also overlays x-staging [128][33] during layer 1
  __shared__ float o3[129*LW];
  __shared__ float Wl[32*36];
  __shared__ float o4s[129];
  __shared__ float xedge[NP];
  __shared__ float diss[NP];
  __shared__ int indeg[NP];
  __shared__ int offs4[NP];
  __shared__ int curp[NP];
  __shared__ unsigned char inlist[2432];   // sum ceil4(deg) <= 2048+3*128
  __shared__ int selidx[20];
  __shared__ float c1buf[16 * 20];
  __shared__ float mpbuf[16 * 10];

  const int t = threadIdx.x;
  const int g = blockIdx.x;
  const int ebase = g * NE;
  const int nbase = g * NP;

  if (t < NP) { xedge[t] = 0.f; indeg[t] = 0; curp[t] = 0; }
  for (int w = t; w < 608; w += NT) ((int*)inlist)[w] = (int)0x80808080u; // pad idx 128
  __syncthreads();

  // ---- edge pass 1: x_edge (over src), in-degree (over dst)
  int er[4], ec[4];
#pragma unroll
  for (int i = 0; i < 4; ++i) {
    const int e = t + i * NT;
    er[i] = eidx[ebase + e] - nbase;
    ec[i] = eidx[E_total + ebase + e] - nbase;
    atomicAdd(&xedge[er[i]], eattr[ebase + e]);
    atomicAdd(&indeg[ec[i]], 1);
  }
  __syncthreads();

  // ---- padded-CSR offsets (segments rounded to 4); dis = rsqrt(1+deg)
  if (t < NP) {
    int s = 0;
    for (int m = 0; m < NP; ++m) { const int dd = (indeg[m] + 3) & ~3; s += (m < t) ? dd : 0; }
    offs4[t] = s;
    diss[t] = rsqrtf(1.0f + (float)indeg[t]);
  }
  __syncthreads();

  // ---- edge pass 2: fill dst-CSR src list (pad slots stay 128)
#pragma unroll
  for (int i = 0; i < 4; ++i) {
    const int p = atomicAdd(&curp[ec[i]], 1);
    inlist[offs4[ec[i]] + p] = (unsigned char)er[i];
  }

  // ---- layer 1: zs1 = ([x | x_edge] @ W1) * dis -> o1 ; x staged [128][33] in o2
  {
    float* xs = o2;
    const int n2 = t & 63, c4 = t >> 6;
    const int sn = t >> 2, sq = t & 3;
    const float* xrow = x + (size_t)(nbase + sn) * NFEAT + sq * 8;
    f4 pv0 = *(const f4*)(xrow);
    f4 pv1 = *(const f4*)(xrow + 4);
    float acc[2][4];
#pragma unroll
    for (int i = 0; i < 2; ++i)
#pragma unroll
      for (int u = 0; u < 4; ++u) acc[i][u] = 0.f;

    for (int fc = 0; fc < NFEAT; fc += 32) {
      __syncthreads();
      { // write prefetched chunk (conflict-free: bank = sn + 8*sq + j)
        float* xd = xs + sn * LW + sq * 8;
#pragma unroll
        for (int j = 0; j < 4; ++j) xd[j] = pv0[j];
#pragma unroll
        for (int j = 0; j < 4; ++j) xd[4 + j] = pv1[j];
      }
      if (t < 256) {  // stage W1 chunk
        const int k = t >> 3, jq = t & 7;
        *(f4*)&Wl[k*36 + jq*4] = *(const f4*)(W1 + (size_t)(fc + k) * 32 + jq * 4);
      }
      if (fc < 96) {  // prefetch next chunk into regs (hides HBM under FMA below)
        pv0 = *(const f4*)(xrow + fc + 32);
        pv1 = *(const f4*)(xrow + fc + 36);
      }
      __syncthreads();
#pragma unroll
      for (int k = 0; k < 32; ++k) {
        f4 w = *(const f4*)&Wl[k*36 + c4*4];
        const float a0 = xs[n2*LW + k];
        const float a1 = xs[(n2+64)*LW + k];
#pragma unroll
        for (int u = 0; u < 4; ++u) { acc[0][u] += a0 * w[u]; acc[1][u] += a1 * w[u]; }
      }
    }
    f4 wlast = *(const f4*)(W1 + 128*32 + c4*4);
#pragma unroll
    for (int i = 0; i < 2; ++i) {
      const int n = n2 + 64*i;
      const float xe = xedge[n], dd = diss[n];
#pragma unroll
      for (int u = 0; u < 4; ++u)
        o1[n*LW + c4*4 + u] = (acc[i][u] + xe * wlast[u]) * dd;
    }
  }
  __syncthreads();
  if (t < LW) { o1[128*LW + t] = 0.f; o2[128*LW + t] = 0.f; o3[128*LW + t] = 0.f; }
  if (t == 0) o4s[128] = 0.f;
  __syncthreads();

  aggregate(o1, b1, inlist, offs4, indeg, diss, t);       // o1 = layer-1 out
  mm32(o1, o2, W2, Wl, diss, t);
  __syncthreads();
  aggregate(o2, b2, inlist, offs4, indeg, diss, t);       // o2 = layer-2 out
  mm32(o2, o3, W3, Wl, diss, t);
  __syncthreads();
  aggregate(o3, b3, inlist, offs4, indeg, diss, t);       // o3 = layer-3 out

  // ---- layer 4 (width 1)
  if (t < NP) {
    float s = 0.f;
#pragma unroll
    for (int f = 0; f < 32; ++f) s += o3[t*LW + f] * W4[f];
    o4s[t] = s * diss[t];
  }
  __syncthreads();
  float s4 = 0.f;
  if (t < NP) {
    s4 = o4s[t];
    const int ps = offs4[t], pe = ps + ((indeg[t] + 3) & ~3);
    for (int p = ps; p < pe; p += 4) {
      const unsigned w = *(const unsigned*)(inlist + p);
#pragma unroll
      for (int b = 0; b < 4; ++b) s4 += o4s[(w >> (8*b)) & 255];
    }
  }
  __syncthreads();
  if (t < NP) o4s[t] = diss[t] * s4 + b4[0];
  __syncthreads();

  // ---- top-k (k=20) rank counting: matches lax.top_k (desc, stable ties)
  if (t < NP) {
    const float sn_ = o4s[t];
    int cnt = 0;
    for (int m = 0; m < NP; ++m) {
      const float sm = o4s[m];
      cnt += (sm > sn_ || (sm == sn_ && m < t)) ? 1 : 0;
    }
    if (cnt < 20) selidx[cnt] = t;
  }
  __syncthreads();

  // ---- c1: [16 ch][20 k], relu
  if (t < 320) {
    const int k = t % 20, ch = t / 20;
    const int nd = selidx[k];
    const float* wr = c1w + ch * 97;
    float s = c1b[ch];
#pragma unroll 8
    for (int d = 0; d < 32; ++d) s += o1[nd*LW + d] * wr[d];
#pragma unroll 8
    for (int d = 0; d < 32; ++d) s += o2[nd*LW + d] * wr[32 + d];
#pragma unroll 8
    for (int d = 0; d < 32; ++d) s += o3[nd*LW + d] * wr[64 + d];
    s += o4s[nd] * wr[96];
    c1buf[ch * 20 + k] = fmaxf(s, 0.f);
  }
  __syncthreads();
  if (t < 160) {  // maxpool(2,2) -> [16][10]
    const int ch = t / 10, p = t % 10;
    mpbuf[ch * 10 + p] = fmaxf(c1buf[ch * 20 + 2*p], c1buf[ch * 20 + 2*p + 1]);
  }
  __syncthreads();
  if (t < 192) {  // conv1d 16->32, k=5 -> [32][6], relu
    const int oc = t / 6, tt = t % 6;
    float s = c2b[oc];
#pragma unroll
    for (int ic = 0; ic < 16; ++ic) {
      const float* wr = c2w + (oc * 16 + ic) * 5;
#pragma unroll
      for (int u = 0; u < 5; ++u) s += mpbuf[ic * 10 + tt + u] * wr[u];
    }
    dense_out[(size_t)g * 192 + t] = fmaxf(s, 0.f);
  }
}

// ---- K2: d1 = relu(dense[1024,192] @ out_w[192,1024] + out_b), 64x64 tiles
__global__ __launch_bounds__(256) void k2_d1(const float* __restrict__ dense,
    const float* __restrict__ out_w, const float* __restrict__ out_b,
    float* __restrict__ d1)
{
  __shared__ float As[32 * 68];  // [k][m] transposed
  __shared__ float Bs[32 * 68];  // [k][n]
  const int t = threadIdx.x;
  const int n0 = blockIdx.x * 64, m0 = blockIdx.y * 64;
  const int r = t & 15, c = t >> 4;
  float acc[4][4];
#pragma unroll
  for (int i = 0; i < 4; ++i)
#pragma unroll
    for (int u = 0; u < 4; ++u) acc[i][u] = 0.f;

  for (int kk = 0; kk < 192; kk += 32) {
    __syncthreads();
    {
      const int m = t >> 2;
      const int kq = (t & 3) * 2;
#pragma unroll
      for (int qq = 0; qq < 2; ++qq) {
        f4 v = *(const f4*)(dense + (size_t)(m0 + m) * 192 + kk + (kq + qq) * 4);
        const int k0 = (kq + qq) * 4;
        As[(k0+0)*68 + m] = v[0]; As[(k0+1)*68 + m] = v[1];
        As[(k0+2)*68 + m] = v[2]; As[(k0+3)*68 + m] = v[3];
      }
    }
    {
      const int k = t >> 3;
      const int nq = (t & 7) * 2;
#pragma unroll
      for (int qq = 0; qq < 2; ++qq) {
        f4 v = *(const f4*)(out_w + (size_t)(kk + k) * 1024 + n0 + (nq + qq) * 4);
        *(f4*)&Bs[k*68 + (nq + qq) * 4] = v;
      }
    }
    __syncthreads();
#pragma unroll
    for (int k = 0; k < 32; ++k) {
      f4 a = *(const f4*)&As[k*68 + r*4];
      f4 b = *(const f4*)&Bs[k*68 + c*4];
#pragma unroll
      for (int i = 0; i < 4; ++i)
#pragma unroll
        for (int u = 0; u < 4; ++u) acc[i][u] += a[i] * b[u];
    }
  }
  f4 bb = *(const f4*)(out_b + n0 + c*4);
#pragma unroll
  for (int i = 0; i < 4; ++i) {
    f4 o;
#pragma unroll
    for (int u = 0; u < 4; ++u) o[u] = fmaxf(acc[i][u] + bb[u], 0.f);
    *(f4*)(d1 + (size_t)(m0 + r*4 + i) * 1024 + n0 + c*4) = o;
  }
}

// ---- K3: partial[z][m][n] = sum_{k in z-slice} d1[m][k]*h1_w[k][n]
// (split-K, plain stores -> no atomics, no init kernel)
__global__ __launch_bounds__(256) void k3_d2(const float* __restrict__ d1,
    const float* __restrict__ h1_w, float* __restrict__ part)
{
  __shared__ float As[32 * 36];
  __shared__ float Bs[32 * 36];
  const int t = threadIdx.x;
  const int m0 = blockIdx.x * 32, n0 = blockIdx.y * 32, ks = blockIdx.z * 128;
  const int r = t & 15, c = t >> 4;
  float a00 = 0.f, a01 = 0.f, a10 = 0.f, a11 = 0.f;

  for (int kk = ks; kk < ks + 128; kk += 32) {
    __syncthreads();
    {
      const int m = t >> 3, kq = t & 7;
      f4 v = *(const f4*)(d1 + (size_t)(m0 + m) * 1024 + kk + kq * 4);
      const int k0 = kq * 4;
      As[(k0+0)*36 + m] = v[0]; As[(k0+1)*36 + m] = v[1];
      As[(k0+2)*36 + m] = v[2]; As[(k0+3)*36 + m] = v[3];
    }
    {
      const int k = t >> 3, nq = t & 7;
      f4 v = *(const f4*)(h1_w + (size_t)(kk + k) * 128 + n0 + nq * 4);
      *(f4*)&Bs[k*36 + nq*4] = v;
    }
    __syncthreads();
#pragma unroll
    for (int k = 0; k < 32; ++k) {
      const float a0 = As[k*36 + r*2], a1 = As[k*36 + r*2 + 1];
      const float b0 = Bs[k*36 + c*2], b1 = Bs[k*36 + c*2 + 1];
      a00 += a0*b0; a01 += a0*b1;
      a10 += a1*b0; a11 += a1*b1;
    }
  }
  float* dst = part + (size_t)blockIdx.z * (1024 * 128);
  dst[(size_t)(m0 + r*2 + 0) * 128 + n0 + c*2 + 0] = a00;
  dst[(size_t)(m0 + r*2 + 0) * 128 + n0 + c*2 + 1] = a01;
  dst[(size_t)(m0 + r*2 + 1) * 128 + n0 + c*2 + 0] = a10;
  dst[(size_t)(m0 + r*2 + 1) * 128 + n0 + c*2 + 1] = a11;
}

// ---- K4: d2 = h1_b + sum_z part[z]; logits = relu(d2) @ h2_w + h2_b; log_softmax
__global__ __launch_bounds__(256) void k4_out(const float* __restrict__ part,
    const float* __restrict__ h1_b, const float* __restrict__ h2_w,
    const float* __restrict__ h2_b, float* __restrict__ outp)
{
  __shared__ float lbuf[16][17];
  const int t = threadIdx.x;
  const int gl = t >> 4, cc = t & 15;
  const int g = blockIdx.x * 16 + gl;
  float s = h2_b[cc];
  for (int k4 = 0; k4 < 32; ++k4) {
    f4 v = *(const f4*)(h1_b + k4 * 4);
#pragma unroll
    for (int z = 0; z < 8; ++z)
      v += *(const f4*)(part + (size_t)z * (1024 * 128) + (size_t)g * 128 + k4 * 4);
#pragma unroll
    for (int i = 0; i < 4; ++i) {
      const float rv = fmaxf(v[i], 0.f);
      s += rv * h2_w[(k4*4 + i) * 16 + cc];
    }
  }
  lbuf[gl][cc] = s;
  __syncthreads();
  float mx = -1e30f;
#pragma unroll
  for (int j = 0; j < 16; ++j) mx = fmaxf(mx, lbuf[gl][j]);
  float se = 0.f;
#pragma unroll
  for (int j = 0; j < 16; ++j) se += expf(lbuf[gl][j] - mx);
  outp[(size_t)g * 16 + cc] = s - mx - logf(se);
}

extern "C" void kernel_launch(void* const* d_in, const int* in_sizes, int n_in,
                              void* d_out, int out_size, void* d_ws, size_t ws_size,
                              hipStream_t stream) {
  const float* x     = (const float*)d_in[0];
  const float* eattr = (const float*)d_in[1];
  const int*   eidx  = (const int*)d_in[2];
  const float* W1 = (const float*)d_in[3];  const float* b1 = (const float*)d_in[4];
  const float* W2 = (const float*)d_in[5];  const float* b2 = (const float*)d_in[6];
  const float* W3 = (const float*)d_in[7];  const float* b3 = (const float*)d_in[8];
  const float* W4 = (const float*)d_in[9];  const float* b4 = (const float*)d_in[10];
  const float* c1w = (const float*)d_in[11]; const float* c1b = (const float*)d_in[12];
  const float* c2w = (const float*)d_in[13]; const float* c2b = (const float*)d_in[14];
  const float* out_w = (const float*)d_in[15]; const float* out_b = (const float*)d_in[16];
  const float* h1_w  = (const float*)d_in[17]; const float* h1_b  = (const float*)d_in[18];
  const float* h2_w  = (const float*)d_in[19]; const float* h2_b  = (const float*)d_in[20];

  const int E_total = in_sizes[1];            // 2,097,152 edges
  const int N_nodes = in_sizes[0] / NFEAT;    // 131,072
  const int G = N_nodes / NP;                 // 1024 graphs

  float* ws    = (float*)d_ws;
  float* dense = ws;                          // [G,192]
  float* d1    = dense + (size_t)G * 192;     // [G,1024]
  float* part  = d1 + (size_t)G * 1024;       // [8][G,128] split-K partials

  k1_gcn<<<G, NT, 0, stream>>>(x, eattr, eidx, W1, b1, W2, b2, W3, b3, W4, b4,
                               c1w, c1b, c2w, c2b, dense, E_total);
  k2_d1<<<dim3(16, G / 64), 256, 0, stream>>>(dense, out_w, out_b, d1);
  k3_d2<<<dim3(G / 32, 4, 8), 256, 0, stream>>>(d1, h1_w, part);
  k4_out<<<G / 16, 256, 0, stream>>>(part, h1_b, h2_w, h2_b, (float*)d_out);
}